// Round 1
// baseline (101.065 us; speedup 1.0000x reference)
//
#include <hip/hip_runtime.h>

#define DD 192
#define HH 224
#define WW 192
#define HWN (HH*WW)              // 43008
#define PLANE ((size_t)DD*HWN)   // 8257536
#define NHC 4
#define HCH 56                   // 4 * 56 = 224
#define NPART (DD*NHC)           // 768
#define SEG 32

// ---------------- K1: 5 products + D-axis 9-tap box sum ----------------
// thread = one (h,w) column; register ring of 9 per product, running sums.
// Ring slot index is static because the d-loop is unrolled by 9.
__global__ __launch_bounds__(256) void k1_dsum(
    const float* __restrict__ I, const float* __restrict__ J,
    float* __restrict__ F, int d0, int d1, int cd_total)
{
    int c = blockIdx.x * 256 + threadIdx.x;          // column in [0, HWN)
    int sd0 = d0 + blockIdx.y * SEG;                 // this block's d-segment
    int sd1 = sd0 + SEG; if (sd1 > d1) sd1 = d1;
    if (sd0 >= d1) return;

    float rA[9], rB[9], rC[9], rD_[9], rE[9];
    float sA=0.f, sB=0.f, sC=0.f, sD=0.f, sE=0.f;
#pragma unroll
    for (int k = 0; k < 9; ++k) { rA[k]=0.f; rB[k]=0.f; rC[k]=0.f; rD_[k]=0.f; rE[k]=0.f; }

    const int start  = sd0 - 4;
    const int nsteps = (sd1 - sd0) + 8;
    const size_t fs  = (size_t)cd_total * HWN;

    for (int base = 0; base < nsteps; base += 9) {
#pragma unroll
        for (int k = 0; k < 9; ++k) {
            int s = base + k;
            if (s < nsteps) {
                int din = start + s;
                float vI = 0.f, vJ = 0.f;
                if (din >= 0 && din < DD) {
                    vI = I[(size_t)din * HWN + c];
                    vJ = J[(size_t)din * HWN + c];
                }
                float vC = vI * vI, vD = vJ * vJ, vE = vI * vJ;
                sA += vI - rA[k];  rA[k]  = vI;
                sB += vJ - rB[k];  rB[k]  = vJ;
                sC += vC - rC[k];  rC[k]  = vC;
                sD += vD - rD_[k]; rD_[k] = vD;
                sE += vE - rE[k];  rE[k]  = vE;
                int dout = din - 4;
                if (dout >= sd0 && dout < sd1) {
                    size_t o = (size_t)(dout - d0) * HWN + c;
                    F[o]        = sA;
                    F[fs + o]   = sB;
                    F[2*fs + o] = sC;
                    F[3*fs + o] = sD;
                    F[4*fs + o] = sE;
                }
            }
        }
    }
}

// ---------------- K2: W-axis box sum (LDS) + H-axis box sum (reg ring) +
//                  NCC math + deterministic block partial ----------------
__global__ __launch_bounds__(192) void k2_whsum(
    const float* __restrict__ F, double* __restrict__ partials,
    int d0, int CD)
{
    int bx   = blockIdx.x;
    int drel = bx >> 2;
    int hc   = bx & 3;
    int d    = d0 + drel;
    int w    = threadIdx.x;          // 0..191
    int h0   = hc * HCH;

    __shared__ float rows[5][WW + 8];
    if (w < 4) {
#pragma unroll
        for (int f = 0; f < 5; ++f) { rows[f][w] = 0.f; rows[f][WW + 4 + w] = 0.f; }
    }

    float rS[5][9];
    float S[5] = {0.f,0.f,0.f,0.f,0.f};
#pragma unroll
    for (int f = 0; f < 5; ++f)
#pragma unroll
        for (int k = 0; k < 9; ++k) rS[f][k] = 0.f;

    float acc = 0.f;
    const size_t fs      = (size_t)CD * HWN;
    const size_t baseoff = (size_t)drel * HWN + (size_t)w;
    const int nsteps = HCH + 8;       // 64

    for (int base = 0; base < nsteps; base += 9) {
#pragma unroll
        for (int k = 0; k < 9; ++k) {
            int s = base + k;
            if (s < nsteps) {               // uniform across block
                int hin = h0 - 4 + s;
                float v[5] = {0.f,0.f,0.f,0.f,0.f};
                if (hin >= 0 && hin < HH) { // uniform
                    size_t o = baseoff + (size_t)hin * WW;
#pragma unroll
                    for (int f = 0; f < 5; ++f) v[f] = F[(size_t)f * fs + o];
                }
                __syncthreads();            // prior reads of rows[] done
#pragma unroll
                for (int f = 0; f < 5; ++f) rows[f][4 + w] = v[f];
                __syncthreads();
#pragma unroll
                for (int f = 0; f < 5; ++f) {
                    float t = 0.f;
#pragma unroll
                    for (int j = 0; j < 9; ++j) t += rows[f][w + j];
                    S[f] += t - rS[f][k];
                    rS[f][k] = t;
                }
                int h = hin - 4;            // = h0 + s - 8
                if (h >= h0) {              // s >= 8; h < h0+HCH guaranteed
                    const float inv = 1.0f / 729.0f;
                    float cross = S[4] - S[0] * S[1] * inv;
                    float varI  = S[2] - S[0] * S[0] * inv;
                    float varJ  = S[3] - S[1] * S[1] * inv;
                    float cc = cross * cross / (varI * varJ + 1e-5f);
                    acc += cc;
                }
            }
        }
    }

    __shared__ float red[192];
    red[w] = acc;
    __syncthreads();
#pragma unroll
    for (int off = 96; off >= 3; off >>= 1) {
        if (w < off) red[w] += red[w + off];
        __syncthreads();
    }
    if (w == 0) partials[d * NHC + hc] = (double)(red[0] + red[1] + red[2]);
}

// ---------------- K3: final reduction of 768 partials ----------------
__global__ __launch_bounds__(256) void k3_reduce(
    const double* __restrict__ partials, float* __restrict__ out)
{
    __shared__ double red[256];
    int t = threadIdx.x;
    double a = 0.0;
    for (int i = t; i < NPART; i += 256) a += partials[i];
    red[t] = a;
    __syncthreads();
    for (int off = 128; off > 0; off >>= 1) {
        if (t < off) red[t] += red[t + off];
        __syncthreads();
    }
    if (t == 0) out[0] = (float)(-red[0] / (double)PLANE);
}

extern "C" void kernel_launch(void* const* d_in, const int* in_sizes, int n_in,
                              void* d_out, int out_size, void* d_ws, size_t ws_size,
                              hipStream_t stream)
{
    const float* I = (const float*)d_in[0];
    const float* J = (const float*)d_in[1];
    float* out = (float*)d_out;

    double* partials = (double*)d_ws;
    const size_t part_bytes = (size_t)NPART * sizeof(double);
    float* F = (float*)((char*)d_ws + part_bytes);

    // Largest d-chunk (divisor of 192) whose 5-field buffer fits in ws.
    static const int divs[13] = {192,96,64,48,32,24,16,12,8,6,4,2,1};
    int CD = 1;
    for (int i = 0; i < 13; ++i) {
        size_t need = part_bytes + 5ull * (size_t)divs[i] * HWN * sizeof(float);
        if (need <= ws_size) { CD = divs[i]; break; }
    }

    for (int d0 = 0; d0 < DD; d0 += CD) {
        int d1 = d0 + CD;
        int nseg = (CD + SEG - 1) / SEG;
        dim3 g1(HWN / 256, nseg);
        k1_dsum<<<g1, dim3(256), 0, stream>>>(I, J, F, d0, d1, CD);
        k2_whsum<<<dim3(CD * NHC), dim3(192), 0, stream>>>(F, partials, d0, CD);
    }
    k3_reduce<<<dim3(1), dim3(256), 0, stream>>>(partials, out);
}